// Round 8
// baseline (1048.316 us; speedup 1.0000x reference)
//
#include <hip/hip_runtime.h>
#include <math.h>

// Encoder forward. B=4, S=2048, D=1024, H=8, hd=128, Dff=4096.
// Reference quirks: multihead(v,q,k) -> Q from v, K from q, V from k;
// layer_norm uses ddof=1 std, no epsilon; no output projection.
//
// All matmuls (5 GEMMs + QK^T + PV) use split-bf16 "x3" MFMA:
// X = Xh + Xl (bf16 hi/lo), X@Y ~= XhYh + XhYl + XlYh (rel err ~3e-5).
// Layout correctness relies ONLY on (a) the m89-verified C/D layout
// (col=lane&15, row=4*(lane>>4)+reg) and (b) A/B operand symmetry:
// staging BOTH operands with the same k->(group,elem) bijection makes the
// result invariant to the hardware's internal k ordering.
// kappa(g,j) = 4g + (j&3) + 16*(j>>2) used everywhere.
//
// R4: T14-lite register prefetch (issue-early) in GEMM + attention.
// R5: V pre-transposed+split (vtrans); attention staging = pure vector copies.
// R6: K-projection emits split-bf16 directly (OUT=2); ksplit deleted.
// R7: T5 s_setprio(1) around attn MFMA clusters (4 unsynced blocks/CU ->
//     m191 regime, +4-7%); NOT applied to lockstep GEMM (m190: ~0%).

#define D_MODEL 1024
#define SEQ 2048
#define BATCH 4
#define NHEAD 8
#define HDIM 128
#define DFF 4096

typedef __attribute__((ext_vector_type(8))) short bf16x8;
typedef __attribute__((ext_vector_type(4))) float f32x4;

// Truncating split: x ~= hi + lo with hi,lo bf16 (error ~2^-16 |x|).
__device__ __forceinline__ void bsplit(float x, ushort& h, ushort& l) {
    unsigned u = __float_as_uint(x) & 0xFFFF0000u;
    h = (ushort)(u >> 16);
    float r = x - __uint_as_float(u);
    l = (ushort)(__float_as_uint(r) >> 16);
}

// async global->LDS, 16B per lane (emits global_load_lds_dwordx4)
__device__ __forceinline__ void gload_lds16(const void* g, void* l) {
    __builtin_amdgcn_global_load_lds(
        (const __attribute__((address_space(1))) void*)g,
        (__attribute__((address_space(3))) void*)l, 16, 0, 0);
}

// ---------------------------------------------------------------- wsplit
// W fp32 [K][N] -> Whi/Wlo bf16 [N][K], element k of each 32-chunk stored at
// pos = (k&3) | (((k>>4)&1)<<2) | ((((k>>2)&3) ^ ((n>>1)&3))<<3).
__global__ __launch_bounds__(256) void wsplit(const float* __restrict__ W,
                                              ushort* __restrict__ Whi,
                                              ushort* __restrict__ Wlo,
                                              int K, int N) {
    __shared__ float T[32][33];
    const int t = threadIdx.x;
    const int k0 = blockIdx.y * 32, n0 = blockIdx.x * 32;
    {
        int i = t >> 3;
        int j = (t & 7) * 4;
        float4 vv = *(const float4*)&W[(size_t)(k0 + i) * N + n0 + j];
        T[i][j] = vv.x; T[i][j + 1] = vv.y; T[i][j + 2] = vv.z; T[i][j + 3] = vv.w;
    }
    __syncthreads();
    {
        int nl = t >> 3;
        int k4 = (t & 7) * 4;
        int n = n0 + nl;
        ushort h[4], l[4];
#pragma unroll
        for (int c = 0; c < 4; ++c) bsplit(T[k4 + c][nl], h[c], l[c]);
        int rem = ((k4 >> 4) & 1) << 2;
        int grp = (k4 >> 2) & 3;
        int gp = grp ^ ((n >> 1) & 3);
        size_t off = (size_t)n * K + k0 + (gp << 3) + rem;
        *(ushort4*)&Whi[off] = make_ushort4(h[0], h[1], h[2], h[3]);
        *(ushort4*)&Wlo[off] = make_ushort4(l[0], l[1], l[2], l[3]);
    }
}

// ---------------------------------------------------------------- GEMM x3
// C[M,N] = A[M,K] @ W[K,N] + bias. BM=BN=128, BK=32, 4 waves (2x2),
// each wave 64x64 = 4x4 fragments of 16x16x32.
// B staged via global_load_lds (pre-swizzled global -> linear LDS).
// A global loads register-prefetched one k-step ahead (T14-lite).
// XCD-aware block swizzle (grid must have nwg % 8 == 0).
// OUT: 0 = fp32 store, 1 = fp32+ReLU, 2 = split-bf16 (Ch/Cl) store.
template <int OUT>
__global__ __launch_bounds__(256, 2) void gemm_x3(const float* __restrict__ A,
                                                  const ushort* __restrict__ Bh_g,
                                                  const ushort* __restrict__ Bl_g,
                                                  const float* __restrict__ bias,
                                                  float* __restrict__ C,
                                                  ushort* __restrict__ Ch,
                                                  ushort* __restrict__ Cl,
                                                  int M, int N, int K) {
    __shared__ ushort Ah[128 * 32], Al[128 * 32], Bh[128 * 32], Bl[128 * 32];

    const int tid = threadIdx.x;
    const int lane = tid & 63;
    const int wid = tid >> 6;
    const int wm = wid >> 1, wn = wid & 1;

    // XCD swizzle: contiguous chunk of the flat grid per XCD
    const unsigned nwg = gridDim.x * gridDim.y;
    const unsigned flat = blockIdx.y * gridDim.x + blockIdx.x;
    const unsigned nf = (flat & 7) * (nwg >> 3) + (flat >> 3);
    const int bm = (nf / gridDim.x) * 128;
    const int bn = (nf % gridDim.x) * 128;

    const int sm = tid >> 1;           // staged A row 0..127
    const int sks = (tid & 1) * 16;    // k-half
    const int swzA = (sm >> 1) & 3;

    const float* Ap = A + (size_t)(bm + sm) * K + sks;

    // B DMA roles: wave w lane l -> LDS elements 512*w + 8*l (+2048 round 1)
    const int brow = 16 * wid + (lane >> 2);
    const int bpos = 8 * (lane & 3);
    const ushort* Bh_r0 = Bh_g + (size_t)(bn + brow) * K + bpos;
    const ushort* Bh_r1 = Bh_g + (size_t)(bn + 64 + brow) * K + bpos;
    const ushort* Bl_r0 = Bl_g + (size_t)(bn + brow) * K + bpos;
    const ushort* Bl_r1 = Bl_g + (size_t)(bn + 64 + brow) * K + bpos;
    const int ldsE = 512 * wid + 8 * lane;

    const int fr = lane & 15;
    const int fg = lane >> 4;

    f32x4 acc[4][4];
#pragma unroll
    for (int i = 0; i < 4; ++i)
#pragma unroll
        for (int j = 0; j < 4; ++j) acc[i][j] = (f32x4){0.f, 0.f, 0.f, 0.f};

    // prefetch A regs for k0 = 0
    float4 av[4];
#pragma unroll
    for (int c = 0; c < 4; ++c) av[c] = *(const float4*)(Ap + 4 * c);

    for (int k0 = 0; k0 < K; k0 += 32) {
        __syncthreads();
        // ---- B staging: 4 async DMA (16B/lane), LDS linear
        gload_lds16(Bh_r0 + k0, &Bh[ldsE]);
        gload_lds16(Bh_r1 + k0, &Bh[2048 + ldsE]);
        gload_lds16(Bl_r0 + k0, &Bl[ldsE]);
        gload_lds16(Bl_r1 + k0, &Bl[2048 + ldsE]);
        // ---- A staging from prefetched regs: split + two-k-block perm + swz
#pragma unroll
        for (int c = 0; c < 4; ++c) {
            int k = sks + 4 * c;
            ushort h0, l0, h1, l1, h2, l2, h3, l3;
            bsplit(av[c].x, h0, l0); bsplit(av[c].y, h1, l1);
            bsplit(av[c].z, h2, l2); bsplit(av[c].w, h3, l3);
            int rem = ((k >> 4) & 1) << 2;
            int grp = (k >> 2) & 3;
            int kp = rem | (((grp ^ swzA) & 3) << 3);
            int eo = sm * 32 + kp;
            *(ushort4*)&Ah[eo] = make_ushort4(h0, h1, h2, h3);
            *(ushort4*)&Al[eo] = make_ushort4(l0, l1, l2, l3);
        }
        __syncthreads();   // drains DMA (vmcnt) + A writes (lgkmcnt)

        // ---- T14: issue next k-step's A loads now; land during MFMA phase
        if (k0 + 32 < K) {
#pragma unroll
            for (int c = 0; c < 4; ++c)
                av[c] = *(const float4*)(Ap + k0 + 32 + 4 * c);
        }

        bf16x8 ah[4], al[4], bh[4], bl[4];
#pragma unroll
        for (int mf = 0; mf < 4; ++mf) {
            int m = wm * 64 + mf * 16 + fr;
            int eo = m * 32 + (((fg ^ ((m >> 1) & 3)) & 3) << 3);
            ah[mf] = *(const bf16x8*)&Ah[eo];
            al[mf] = *(const bf16x8*)&Al[eo];
        }
#pragma unroll
        for (int nf2 = 0; nf2 < 4; ++nf2) {
            int n = wn * 64 + nf2 * 16 + fr;
            int eo = n * 32 + (((fg ^ ((n >> 1) & 3)) & 3) << 3);
            bh[nf2] = *(const bf16x8*)&Bh[eo];
            bl[nf2] = *(const bf16x8*)&Bl[eo];
        }
#pragma unroll
        for (int mf = 0; mf < 4; ++mf)
#pragma unroll
            for (int nf2 = 0; nf2 < 4; ++nf2) {
                acc[mf][nf2] = __builtin_amdgcn_mfma_f32_16x16x32_bf16(ah[mf], bh[nf2], acc[mf][nf2], 0, 0, 0);
                acc[mf][nf2] = __builtin_amdgcn_mfma_f32_16x16x32_bf16(ah[mf], bl[nf2], acc[mf][nf2], 0, 0, 0);
                acc[mf][nf2] = __builtin_amdgcn_mfma_f32_16x16x32_bf16(al[mf], bh[nf2], acc[mf][nf2], 0, 0, 0);
            }
    }

    // C/D layout: col = lane&15, row = 4*(lane>>4) + reg  (m89-verified)
#pragma unroll
    for (int nf2 = 0; nf2 < 4; ++nf2) {
        int col = bn + wn * 64 + nf2 * 16 + fr;
        float bv = bias[col];
#pragma unroll
        for (int mf = 0; mf < 4; ++mf) {
            int row0 = bm + wm * 64 + mf * 16 + fg * 4;
#pragma unroll
            for (int r = 0; r < 4; ++r) {
                float vv = acc[mf][nf2][r] + bv;
                if (OUT == 1) vv = fmaxf(vv, 0.f);
                if (OUT == 2) {
                    ushort hh, ll;
                    bsplit(vv, hh, ll);
                    Ch[(size_t)(row0 + r) * N + col] = hh;
                    Cl[(size_t)(row0 + r) * N + col] = ll;
                } else {
                    C[(size_t)(row0 + r) * N + col] = vv;
                }
            }
        }
    }
}

// ---------------------------------------------------------------- vtrans
// Vb fp32 [B*S][D] -> VhT/VlT split-bf16 [(b*H+h)*HDIM + dv][SEQ].
// Grid (S/32, D/32, B), 32x32 LDS tile transpose.
__global__ __launch_bounds__(256) void vtrans(const float* __restrict__ Vb,
                                              ushort* __restrict__ VhT,
                                              ushort* __restrict__ VlT) {
    __shared__ float T[32][33];
    const int t = threadIdx.x;
    const int s0 = blockIdx.x * 32, d0 = blockIdx.y * 32, b = blockIdx.z;
    {
        int i = t >> 3;            // s-local
        int j = (t & 7) * 4;       // d-local
        float4 vv = *(const float4*)&Vb[(size_t)(b * SEQ + s0 + i) * D_MODEL + d0 + j];
        T[i][j] = vv.x; T[i][j + 1] = vv.y; T[i][j + 2] = vv.z; T[i][j + 3] = vv.w;
    }
    __syncthreads();
    {
        int dl = t >> 3;           // d-local 0..31
        int s4 = (t & 7) * 4;      // s-local quad
        int d = d0 + dl;
        int h = d >> 7, dv = d & 127;
        ushort hh[4], ll[4];
#pragma unroll
        for (int c = 0; c < 4; ++c) bsplit(T[s4 + c][dl], hh[c], ll[c]);
        size_t off = (size_t)((b * NHEAD + h) * HDIM + dv) * SEQ + s0 + s4;
        *(ushort4*)&VhT[off] = make_ushort4(hh[0], hh[1], hh[2], hh[3]);
        *(ushort4*)&VlT[off] = make_ushort4(ll[0], ll[1], ll[2], ll[3]);
    }
}

// ---------------------------------------------------------------- attention
// Flash-style, x3 MFMA. 1024 blocks (XCD-swizzled), 4 waves x 16 q-rows.
// QK^T swapped: D[k][q] = mfma(A=K, B=Q)  -> per-q state lives at lane&15=q.
// P accumulator regs feed PV's A-operand directly; V pre-transposed+split
// so staging is pure vector copies. K pre-split by proj epilogue; K/V
// reg-prefetched one tile ahead (T14). T5 setprio around MFMA clusters.
#define QB 64
#define KB 32
#define VP 40   // padded V row stride (elements): 80B rows, 16B-aligned reads

__global__ __launch_bounds__(256, 2) void attn_mfma(const float* __restrict__ Q,
                                                    const ushort* __restrict__ KhG,
                                                    const ushort* __restrict__ KlG,
                                                    const ushort* __restrict__ VhT,
                                                    const ushort* __restrict__ VlT,
                                                    float* __restrict__ O) {
    __shared__ ushort Kh[KB * 128], Kl[KB * 128];   // [k-row][pos(d)] swizzled
    __shared__ ushort Vh[128 * VP], Vl[128 * VP];   // [dv][pos(k)] padded

    const int tid = threadIdx.x;
    const int lane = tid & 63;
    const int wid = tid >> 6;
    const int g = lane >> 4;
    const int fr = lane & 15;

    // XCD swizzle over flat grid of 1024 (= 32 qblk x 8 h x 4 b)
    const unsigned nf = (blockIdx.x & 7) * 128 + (blockIdx.x >> 3);
    const int qb = nf & 31;
    const int h = (nf >> 5) & 7;
    const int b = nf >> 8;
    const int q0 = qb * QB;
    const size_t base = ((size_t)b * SEQ) * D_MODEL + (size_t)h * HDIM;

    // Q fragments in registers (pre-scaled by 1/sqrt(hd)), kept for all tiles.
    const float scale = 0.08838834764831843f;
    bf16x8 qh[4], ql[4];
    {
        const float* Qrow = Q + base + (size_t)(q0 + wid * 16 + fr) * D_MODEL;
#pragma unroll
        for (int c = 0; c < 4; ++c) {
            float4 xa = *(const float4*)(Qrow + c * 32 + 4 * g);
            float4 xb = *(const float4*)(Qrow + c * 32 + 16 + 4 * g);
            float f[8] = {xa.x, xa.y, xa.z, xa.w, xb.x, xb.y, xb.z, xb.w};
            bf16x8 th, tl;
#pragma unroll
            for (int j = 0; j < 8; ++j) {
                ushort hh, ll;
                bsplit(f[j] * scale, hh, ll);
                th[j] = (short)hh; tl[j] = (short)ll;
            }
            qh[c] = th; ql[c] = tl;
        }
    }

    // K staging roles: thread -> k-row kr, d-segment d0..d0+15
    const int kr = tid >> 3;
    const int d0 = (tid & 7) * 16;
    const ushort* Khp = KhG + base + (size_t)kr * D_MODEL + d0;
    const ushort* Klp = KlG + base + (size_t)kr * D_MODEL + d0;

    // V staging roles: thread -> k-quad vq, dv rows {vdg + 32j}
    const int vq = tid & 7;
    const int vdg = tid >> 3;
    const size_t vbase = (size_t)((b * NHEAD + h) * HDIM + vdg) * SEQ + 4 * vq;
    const int vgk8 = (vq & 3) * 8;     // position group base
    const int vpb4 = vq & 4;           // +4 for upper k-half

    float m_run = -INFINITY, l_run = 0.f;
    f32x4 out[8];
#pragma unroll
    for (int f = 0; f < 8; ++f) out[f] = (f32x4){0.f, 0.f, 0.f, 0.f};

    // prefetch K/V regs for tile 0
    ushort4 kph[4], kpl[4], vph[4], vpl[4];
#pragma unroll
    for (int i = 0; i < 4; ++i) {
        kph[i] = *(const ushort4*)(Khp + 4 * i);
        kpl[i] = *(const ushort4*)(Klp + 4 * i);
        vph[i] = *(const ushort4*)(VhT + vbase + (size_t)(32 * i) * SEQ);
        vpl[i] = *(const ushort4*)(VlT + vbase + (size_t)(32 * i) * SEQ);
    }

    for (int k0 = 0; k0 < SEQ; k0 += KB) {
        __syncthreads();
        // ---- stage K from regs: [kr][pos(d)], 16-slot XOR swizzle by (kr&15)
#pragma unroll
        for (int i = 0; i < 4; ++i) {
            int d = d0 + 4 * i;
            int s = ((d >> 5) << 2) | ((d >> 2) & 3);
            int sp = s ^ (kr & 15);
            int eo = kr * 128 + sp * 8 + ((d >> 4) & 1) * 4;
            *(ushort4*)&Kh[eo] = kph[i];
            *(ushort4*)&Kl[eo] = kpl[i];
        }
        // ---- stage V from regs: [dv][pos(k)], padded rows, vector writes
#pragma unroll
        for (int i = 0; i < 4; ++i) {
            int eo = (vdg + 32 * i) * VP + vgk8 + vpb4;
            *(ushort4*)&Vh[eo] = vph[i];
            *(ushort4*)&Vl[eo] = vpl[i];
        }
        __syncthreads();

        // ---- T14: issue next tile's K/V loads now; land during MFMA phase
        if (k0 + KB < SEQ) {
#pragma unroll
            for (int i = 0; i < 4; ++i) {
                kph[i] = *(const ushort4*)(Khp + (size_t)(k0 + KB) * D_MODEL + 4 * i);
                kpl[i] = *(const ushort4*)(Klp + (size_t)(k0 + KB) * D_MODEL + 4 * i);
                vph[i] = *(const ushort4*)(VhT + vbase + (size_t)(32 * i) * SEQ + k0 + KB);
                vpl[i] = *(const ushort4*)(VlT + vbase + (size_t)(32 * i) * SEQ + k0 + KB);
            }
        }

        // ---- QK^T: S0 = k-rows 0..15 of tile, S1 = 16..31 (cols = wave's q)
        f32x4 S0 = (f32x4){0.f, 0.f, 0.f, 0.f};
        f32x4 S1 = (f32x4){0.f, 0.f, 0.f, 0.f};
        __builtin_amdgcn_s_setprio(1);
#pragma unroll
        for (int c = 0; c < 4; ++c) {
            int sl = ((c << 2) | g) ^ fr;
            int eo0 = fr * 128 + sl * 8;
            int eo1 = (16 + fr) * 128 + sl * 8;
            bf16x8 a0h = *(const bf16x8*)&Kh[eo0];
            bf16x8 a0l = *(const bf16x8*)&Kl[eo0];
            bf16x8 a1h = *(const bf16x8*)&Kh[eo1];
            bf16x8 a1l = *(const bf16x8*)&Kl[eo1];
            S0 = __builtin_amdgcn_mfma_f32_16x16x32_bf16(a0h, qh[c], S0, 0, 0, 0);
            S0 = __builtin_amdgcn_mfma_f32_16x16x32_bf16(a0h, ql[c], S0, 0, 0, 0);
            S0 = __builtin_amdgcn_mfma_f32_16x16x32_bf16(a0l, qh[c], S0, 0, 0, 0);
            S1 = __builtin_amdgcn_mfma_f32_16x16x32_bf16(a1h, qh[c], S1, 0, 0, 0);
            S1 = __builtin_amdgcn_mfma_f32_16x16x32_bf16(a1h, ql[c], S1, 0, 0, 0);
            S1 = __builtin_amdgcn_mfma_f32_16x16x32_bf16(a1l, qh[c], S1, 0, 0, 0);
        }
        __builtin_amdgcn_s_setprio(0);

        // ---- online softmax (per q = lane&15; lanes l, l^16, l^32, l^48 share q)
        float mx = fmaxf(fmaxf(fmaxf(S0[0], S0[1]), fmaxf(S0[2], S0[3])),
                         fmaxf(fmaxf(S1[0], S1[1]), fmaxf(S1[2], S1[3])));
        mx = fmaxf(mx, __shfl_xor(mx, 16, 64));
        mx = fmaxf(mx, __shfl_xor(mx, 32, 64));
        float mn = fmaxf(m_run, mx);
        float al = __expf(m_run - mn);
        float p[8];
        p[0] = __expf(S0[0] - mn); p[1] = __expf(S0[1] - mn);
        p[2] = __expf(S0[2] - mn); p[3] = __expf(S0[3] - mn);
        p[4] = __expf(S1[0] - mn); p[5] = __expf(S1[1] - mn);
        p[6] = __expf(S1[2] - mn); p[7] = __expf(S1[3] - mn);
        float ps = p[0] + p[1] + p[2] + p[3] + p[4] + p[5] + p[6] + p[7];
        ps += __shfl_xor(ps, 16, 64);
        ps += __shfl_xor(ps, 32, 64);
        l_run = l_run * al + ps;
        m_run = mn;

        // ---- P -> bf16 hi/lo A-fragment (j0-3 = S0 regs, j4-7 = S1 regs)
        bf16x8 ph, pl;
#pragma unroll
        for (int j = 0; j < 8; ++j) {
            ushort hh, ll;
            bsplit(p[j], hh, ll);
            ph[j] = (short)hh; pl[j] = (short)ll;
        }

        // ---- rescale running output by alpha(q); out reg r has q = 4g+r
        float alr0 = __shfl(al, 4 * g + 0, 64);
        float alr1 = __shfl(al, 4 * g + 1, 64);
        float alr2 = __shfl(al, 4 * g + 2, 64);
        float alr3 = __shfl(al, 4 * g + 3, 64);
#pragma unroll
        for (int f = 0; f < 8; ++f) {
            out[f][0] *= alr0; out[f][1] *= alr1;
            out[f][2] *= alr2; out[f][3] *= alr3;
        }

        // ---- PV: out[q][dv] += P @ V   (B-frag: lane&15 = dv within f-block)
        __builtin_amdgcn_s_setprio(1);
#pragma unroll
        for (int f = 0; f < 8; ++f) {
            int dv = f * 16 + fr;
            int eo = dv * VP + g * 8;
            bf16x8 vh = *(const bf16x8*)&Vh[eo];
            bf16x8 vl = *(const bf16x8*)&Vl[eo];
            out[f] = __builtin_amdgcn_mfma_f32_16x16x32_bf16(ph, vh, out[f], 0, 0, 0);
            out[f] = __builtin_amdgcn_mfma_f32_16x16x32_bf16(ph, vl, out[f], 0, 0, 0);
            out[f] = __builtin_amdgcn_mfma_f32_16x16x32_bf16(pl, vh, out[f], 0, 0, 0);
        }
        __builtin_amdgcn_s_setprio(0);
    }

    // ---- finalize: divide by l(q), write O[q][h*128+dv]
    float li0 = 1.f / __shfl(l_run, 4 * g + 0, 64);
    float li1 = 1.f / __shfl(l_run, 4 * g + 1, 64);
    float li2 = 1.f / __shfl(l_run, 4 * g + 2, 64);
    float li3 = 1.f / __shfl(l_run, 4 * g + 3, 64);
#pragma unroll
    for (int f = 0; f < 8; ++f) {
        size_t o0 = base + (size_t)(q0 + wid * 16 + 4 * g) * D_MODEL + f * 16 + fr;
        O[o0]                = out[f][0] * li0;
        O[o0 + D_MODEL]      = out[f][1] * li1;
        O[o0 + 2 * D_MODEL]  = out[f][2] * li2;
        O[o0 + 3 * D_MODEL]  = out[f][3] * li3;
    }
}

// ---------------------------------------------------------------- add + layernorm
// out[row] = addin[row] + (x[row]-mean)/std, ddof=1, no eps. out may alias x.
__global__ __launch_bounds__(256) void add_ln(const float* __restrict__ addin,
                                              const float* __restrict__ x,
                                              float* __restrict__ out) {
    __shared__ float red[8];
    const int tid = threadIdx.x;
    const size_t off = (size_t)blockIdx.x * D_MODEL + tid * 4;

    float4 v = *(const float4*)&x[off];
    float s = v.x + v.y + v.z + v.w;
#pragma unroll
    for (int msk = 1; msk < 64; msk <<= 1) s += __shfl_xor(s, msk, 64);
    if ((tid & 63) == 0) red[tid >> 6] = s;
    __syncthreads();
    s = red[0] + red[1] + red[2] + red[3];
    const float mean = s * (1.f / 1024.f);

    float dx = v.x - mean, dy = v.y - mean, dz = v.z - mean, dw = v.w - mean;
    float q = dx * dx + dy * dy + dz * dz + dw * dw;
#pragma unroll
    for (int msk = 1; msk < 64; msk <<= 1) q += __shfl_xor(q, msk, 64);
    if ((tid & 63) == 0) red[4 + (tid >> 6)] = q;
    __syncthreads();
    q = red[4] + red[5] + red[6] + red[7];
    const float inv_std = 1.f / sqrtf(q * (1.f / 1023.f));

    float4 a = *(const float4*)&addin[off];
    float4 o;
    o.x = a.x + dx * inv_std;
    o.y = a.y + dy * inv_std;
    o.z = a.z + dz * inv_std;
    o.w = a.w + dw * inv_std;
    *(float4*)&out[off] = o;
}

// ---------------------------------------------------------------- launch
extern "C" void kernel_launch(void* const* d_in, const int* in_sizes, int n_in,
                              void* d_out, int out_size, void* d_ws, size_t ws_size,
                              hipStream_t stream) {
    const float* q  = (const float*)d_in[0];
    const float* k  = (const float*)d_in[1];
    const float* v  = (const float*)d_in[2];
    const float* Wq = (const float*)d_in[3];
    const float* bq = (const float*)d_in[4];
    const float* Wk = (const float*)d_in[5];
    const float* bk = (const float*)d_in[6];
    const float* Wv = (const float*)d_in[7];
    const float* bv = (const float*)d_in[8];
    const float* W1 = (const float*)d_in[9];
    const float* b1 = (const float*)d_in[10];
    const float* W2 = (const float*)d_in[11];
    const float* b2 = (const float*)d_in[12];
    float* out = (float*)d_out;

    const int M = BATCH * SEQ;                     // 8192
    const size_t nBSD = (size_t)M * D_MODEL;       // 8388608
    const size_t szD2 = (size_t)D_MODEL * D_MODEL;
    const size_t szW1 = (size_t)D_MODEL * DFF;
    const size_t wtElems = 6 * szD2 + 4 * szW1;    // 23068672
    const size_t NEED = wtElems * 2 + 5 * nBSD * 4;  // ~214 MB
    if (ws_size < NEED) return;

    ushort* wt = (ushort*)d_ws;
    ushort* wqh = wt;               ushort* wql = wqh + szD2;
    ushort* wkh = wql + szD2;       ushort* wkl = wkh + szD2;
    ushort* wvh = wkl + szD2;       ushort* wvl = wvh + szD2;
    ushort* w1h = wvl + szD2;       ushort* w1l = w1h + szW1;
    ushort* w2h = w1l + szW1;       ushort* w2l = w2h + szW1;

    float* fa   = (float*)(wt + wtElems);   // 5 regions x 32 MB
    float* res1 = fa;                       // R0: VhT/VlT (attn) -> res1 (late)
    float* Qb   = fa + nBSD;                // R1
    float* Kx   = fa + 2 * nBSD;            // R2: KhG/KlG (split K, direct)
    float* Vb   = fa + 3 * nBSD;            // R3: Vb
    float* tail = fa + 4 * nBSD;            // R4: MH
    float* MH     = tail;
    float* hidden = Qb;                     // [M,DFF] spans R1..R4 during FFN

    ushort* VhT = (ushort*)res1;   ushort* VlT = VhT + nBSD;   // in R0
    ushort* KhG = (ushort*)Kx;     ushort* KlG = KhG + nBSD;   // in R2

    dim3 blk(256);

    wsplit<<<dim3(D_MODEL / 32, D_MODEL / 32), blk, 0, stream>>>(Wq, wqh, wql, D_MODEL, D_MODEL);
    wsplit<<<dim3(D_MODEL / 32, D_MODEL / 32), blk, 0, stream>>>(Wk, wkh, wkl, D_MODEL, D_MODEL);
    wsplit<<<dim3(D_MODEL / 32, D_MODEL / 32), blk, 0, stream>>>(Wv, wvh, wvl, D_MODEL, D_MODEL);
    wsplit<<<dim3(DFF / 32, D_MODEL / 32), blk, 0, stream>>>(W1, w1h, w1l, D_MODEL, DFF);
    wsplit<<<dim3(D_MODEL / 32, DFF / 32), blk, 0, stream>>>(W2, w2h, w2l, DFF, D_MODEL);

    // projections (reference swaps inputs: Q<-v, K<-q, V<-k)
    gemm_x3<0><<<dim3(D_MODEL / 128, M / 128), blk, 0, stream>>>(v, wqh, wql, bq, Qb, nullptr, nullptr, M, D_MODEL, D_MODEL);
    gemm_x3<2><<<dim3(D_MODEL / 128, M / 128), blk, 0, stream>>>(q, wkh, wkl, bk, nullptr, KhG, KlG, M, D_MODEL, D_MODEL);
    gemm_x3<0><<<dim3(D_MODEL / 128, M / 128), blk, 0, stream>>>(k, wvh, wvl, bv, Vb, nullptr, nullptr, M, D_MODEL, D_MODEL);

    // V -> transposed split-bf16 (into R0)
    vtrans<<<dim3(SEQ / 32, D_MODEL / 32, BATCH), blk, 0, stream>>>(Vb, VhT, VlT);

    attn_mfma<<<dim3(SEQ / QB * NHEAD * BATCH), blk, 0, stream>>>(Qb, KhG, KlG, VhT, VlT, MH);

    // res1 = q + LN(mh)  (overwrites VhT/VlT region, now dead)
    add_ln<<<dim3(M), blk, 0, stream>>>(q, MH, res1);

    gemm_x3<1><<<dim3(DFF / 128, M / 128), blk, 0, stream>>>(res1, w1h, w1l, b1, hidden, nullptr, nullptr, M, DFF, D_MODEL);
    gemm_x3<0><<<dim3(D_MODEL / 128, M / 128), blk, 0, stream>>>(hidden, w2h, w2l, b2, out, nullptr, nullptr, M, D_MODEL, DFF);

    add_ln<<<dim3(M), blk, 0, stream>>>(res1, out, out);
}